// Round 1
// baseline (1028.005 us; speedup 1.0000x reference)
//
#include <hip/hip_runtime.h>

#define TOKENS 8192
#define DIM 1024
#define NEXP 8
#define FDIM 4096

typedef __bf16 bf16x8 __attribute__((ext_vector_type(8)));
typedef float f32x4 __attribute__((ext_vector_type(4)));

__device__ __forceinline__ unsigned short f2bf(float f) {
  unsigned u = __builtin_bit_cast(unsigned, f);
  u += 0x7fffu + ((u >> 16) & 1u);
  return (unsigned short)(u >> 16);
}

__device__ __forceinline__ void gload16(const void* g, void* l) {
  __builtin_amdgcn_global_load_lds(
      (const __attribute__((address_space(1))) unsigned int*)g,
      (__attribute__((address_space(3))) unsigned int*)l, 16, 0, 0);
}

// ---------------- router: fp32 logits, softmax, top-2, cast hs to bf16 ----------------
__global__ void zero_counts_kernel(int* counts) {
  if (threadIdx.x < NEXP) counts[threadIdx.x] = 0;
}

__global__ void scan_kernel(const int* counts, int* offs) {
  if (threadIdx.x == 0) {
    int s = 0;
    for (int e = 0; e < NEXP; ++e) { offs[e] = s; s += counts[e]; }
    offs[NEXP] = s;
  }
}

__global__ void router_kernel(const float* __restrict__ hs,
                              const float* __restrict__ gw,
                              const float* __restrict__ gb,
                              int* __restrict__ counts,
                              int* __restrict__ tok_idx,
                              float* __restrict__ tok_w,
                              unsigned short* __restrict__ hs_bf) {
  const int lane = threadIdx.x & 63;
  const int wid = threadIdx.x >> 6;
  const int t = blockIdx.x * 4 + wid;
  const float* row = hs + (size_t)t * DIM;

  float x[16];
  const float4* r4 = (const float4*)(row + lane * 16);
#pragma unroll
  for (int i = 0; i < 4; ++i) {
    float4 v = r4[i];
    x[i * 4 + 0] = v.x; x[i * 4 + 1] = v.y; x[i * 4 + 2] = v.z; x[i * 4 + 3] = v.w;
  }

  float acc[8];
#pragma unroll
  for (int e = 0; e < 8; ++e) acc[e] = 0.f;
#pragma unroll
  for (int i = 0; i < 16; ++i) {
    const int d = lane * 16 + i;
    const float4* g4 = (const float4*)(gw + (size_t)d * 8);
    float4 g0 = g4[0], g1 = g4[1];
    const float xv = x[i];
    acc[0] += xv * g0.x; acc[1] += xv * g0.y; acc[2] += xv * g0.z; acc[3] += xv * g0.w;
    acc[4] += xv * g1.x; acc[5] += xv * g1.y; acc[6] += xv * g1.z; acc[7] += xv * g1.w;
  }
#pragma unroll
  for (int sh = 1; sh < 64; sh <<= 1) {
#pragma unroll
    for (int e = 0; e < 8; ++e) acc[e] += __shfl_xor(acc[e], sh, 64);
  }
#pragma unroll
  for (int e = 0; e < 8; ++e) acc[e] += gb[e];

  float mx = acc[0];
#pragma unroll
  for (int e = 1; e < 8; ++e) mx = fmaxf(mx, acc[e]);
  float p[8];
  float sum = 0.f;
#pragma unroll
  for (int e = 0; e < 8; ++e) { p[e] = __expf(acc[e] - mx); sum += p[e]; }
  const float inv = 1.0f / sum;

  int i0 = 0; float b0 = p[0];
#pragma unroll
  for (int e = 1; e < 8; ++e) if (p[e] > b0) { b0 = p[e]; i0 = e; }
  int i1 = -1; float b1v = -1.f;
#pragma unroll
  for (int e = 0; e < 8; ++e) if (e != i0 && p[e] > b1v) { b1v = p[e]; i1 = e; }

  if (lane == 0) {
    int pos0 = atomicAdd(&counts[i0], 1);
    tok_idx[i0 * TOKENS + pos0] = t;
    tok_w[i0 * TOKENS + pos0] = b0 * inv;
    int pos1 = atomicAdd(&counts[i1], 1);
    tok_idx[i1 * TOKENS + pos1] = t;
    tok_w[i1 * TOKENS + pos1] = b1v * inv;
  }

  // cast hidden row to bf16
  unsigned short us[16];
#pragma unroll
  for (int i = 0; i < 16; ++i) us[i] = f2bf(x[i]);
  uint4 o0, o1;
  o0.x = (unsigned)us[0] | ((unsigned)us[1] << 16);
  o0.y = (unsigned)us[2] | ((unsigned)us[3] << 16);
  o0.z = (unsigned)us[4] | ((unsigned)us[5] << 16);
  o0.w = (unsigned)us[6] | ((unsigned)us[7] << 16);
  o1.x = (unsigned)us[8] | ((unsigned)us[9] << 16);
  o1.y = (unsigned)us[10] | ((unsigned)us[11] << 16);
  o1.z = (unsigned)us[12] | ((unsigned)us[13] << 16);
  o1.w = (unsigned)us[14] | ((unsigned)us[15] << 16);
  uint4* dst = (uint4*)(hs_bf + (size_t)t * DIM + lane * 16);
  dst[0] = o0;
  dst[1] = o1;
}

// ---------------- transpose + cast weights: src[e][R][C] f32 -> dst[e][C][R] bf16 ----------------
__global__ void cast_transpose_kernel(const float* __restrict__ src,
                                      unsigned short* __restrict__ dst,
                                      int R, int C) {
  __shared__ float tile[64][65];
  const int e = blockIdx.z;
  const int r0 = blockIdx.y * 64;
  const int c0 = blockIdx.x * 64;
  const float* s = src + (size_t)e * R * C;
  unsigned int* d = (unsigned int*)(dst + (size_t)e * R * C);

#pragma unroll
  for (int i = 0; i < 16; ++i) {
    const int idx = threadIdx.x + i * 256;
    const int r = idx >> 6;
    const int c = idx & 63;
    tile[r][c] = s[(size_t)(r0 + r) * C + (c0 + c)];
  }
  __syncthreads();
#pragma unroll
  for (int i = 0; i < 8; ++i) {
    const int idx = threadIdx.x + i * 256;
    const int c = idx >> 5;
    const int r = (idx & 31) * 2;
    unsigned pk = (unsigned)f2bf(tile[r][c]) | ((unsigned)f2bf(tile[r + 1][c]) << 16);
    d[((size_t)(c0 + c) * R + (r0 + r)) >> 1] = pk;
  }
}

// ---------------- init: out = input_tensor ----------------
__global__ void copy_kernel(float* __restrict__ out, const float* __restrict__ in, int n4) {
  int i = blockIdx.x * blockDim.x + threadIdx.x;
  const int stride = gridDim.x * blockDim.x;
  for (; i < n4; i += stride) {
    ((float4*)out)[i] = ((const float4*)in)[i];
  }
}

// ---------------- grouped GEMM ----------------
// MODE 0: h = gelu(gather(hs_bf) @ w1t^T + b1)   (K=1024, N=4096), write h_buf bf16
// MODE 1: out[tok] += w * (h_buf @ w2t^T + b2)   (K=4096, N=1024), atomic f32
template<int MODE, int K, int N>
__global__ __launch_bounds__(256)
void moe_gemm(const unsigned short* __restrict__ Abase,
              const unsigned short* __restrict__ Bbase,
              const float* __restrict__ bias,
              const int* __restrict__ counts,
              const int* __restrict__ offs,
              const int* __restrict__ tok_idx,
              const float* __restrict__ tok_w,
              unsigned short* __restrict__ hout,
              float* __restrict__ out) {
  constexpr int BM = 128, BN = 128, BK = 64;
  __shared__ __align__(16) unsigned char sm[(BM + BN) * BK * 2];
  unsigned char* As = sm;
  unsigned char* Bs = sm + BM * BK * 2;

  const int e = blockIdx.z;
  const int cnt = counts[e];
  const int m0 = blockIdx.y * BM;
  if (m0 >= cnt) return;
  const int n0 = blockIdx.x * BN;
  const int goff = offs[e];

  const int tid = threadIdx.x;
  const int lane = tid & 63;
  const int wid = tid >> 6;
  const int wr = wid >> 1;
  const int wc = wid & 1;

  const unsigned char* a_src[4];
  const unsigned char* b_src[4];
  unsigned char* a_dst[4];
  unsigned char* b_dst[4];
  const unsigned char* Bexp = (const unsigned char*)(Bbase + (size_t)e * K * N);

#pragma unroll
  for (int j = 0; j < 4; ++j) {
    const int row = wid * 32 + j * 8 + (lane >> 3);
    const int ch = (lane & 7) ^ (row & 7);  // source pre-swizzle for conflict-free ds_read
    const int gm = m0 + row;
    const int gmc = gm < cnt ? gm : cnt - 1;
    size_t arow;
    if (MODE == 0) {
      arow = (size_t)tok_idx[e * TOKENS + gmc] * K;
    } else {
      arow = (size_t)(goff + gmc) * K;
    }
    a_src[j] = (const unsigned char*)(Abase + arow) + ch * 16;
    b_src[j] = Bexp + (size_t)(n0 + row) * (K * 2) + ch * 16;
    a_dst[j] = As + (wid * 32 + j * 8) * (BK * 2);
    b_dst[j] = Bs + (wid * 32 + j * 8) * (BK * 2);
  }

  f32x4 acc[4][4];
  const f32x4 fz = {0.f, 0.f, 0.f, 0.f};
#pragma unroll
  for (int mi = 0; mi < 4; ++mi)
#pragma unroll
    for (int ni = 0; ni < 4; ++ni) acc[mi][ni] = fz;

  for (int kt = 0; kt < K / BK; ++kt) {
    const int kb = kt * (BK * 2);
#pragma unroll
    for (int j = 0; j < 4; ++j) gload16(a_src[j] + kb, a_dst[j]);
#pragma unroll
    for (int j = 0; j < 4; ++j) gload16(b_src[j] + kb, b_dst[j]);
    __syncthreads();
#pragma unroll
    for (int kk = 0; kk < 2; ++kk) {
      bf16x8 af[4], bfr[4];
#pragma unroll
      for (int mi = 0; mi < 4; ++mi) {
        const int r = wr * 64 + mi * 16 + (lane & 15);
        const int c = (kk * 4 + (lane >> 4)) ^ (r & 7);
        af[mi] = *(const bf16x8*)(As + r * 128 + c * 16);
      }
#pragma unroll
      for (int ni = 0; ni < 4; ++ni) {
        const int r = wc * 64 + ni * 16 + (lane & 15);
        const int c = (kk * 4 + (lane >> 4)) ^ (r & 7);
        bfr[ni] = *(const bf16x8*)(Bs + r * 128 + c * 16);
      }
#pragma unroll
      for (int mi = 0; mi < 4; ++mi)
#pragma unroll
        for (int ni = 0; ni < 4; ++ni)
          acc[mi][ni] = __builtin_amdgcn_mfma_f32_16x16x32_bf16(af[mi], bfr[ni], acc[mi][ni], 0, 0, 0);
    }
    __syncthreads();
  }

  if (MODE == 0) {
#pragma unroll
    for (int ni = 0; ni < 4; ++ni) {
      const int f = n0 + wc * 64 + ni * 16 + (lane & 15);
      const float bv = bias[e * N + f];
#pragma unroll
      for (int mi = 0; mi < 4; ++mi) {
#pragma unroll
        for (int j = 0; j < 4; ++j) {
          const int ml = wr * 64 + mi * 16 + (lane >> 4) * 4 + j;
          const int gm = m0 + ml;
          if (gm < cnt) {
            const float v = acc[mi][ni][j] + bv;
            const float g = 0.5f * v *
                (1.0f + tanhf(0.7978845608028654f * (v + 0.044715f * v * v * v)));
            hout[(size_t)(goff + gm) * N + f] = f2bf(g);
          }
        }
      }
    }
  } else {
#pragma unroll
    for (int mi = 0; mi < 4; ++mi) {
#pragma unroll
      for (int j = 0; j < 4; ++j) {
        const int ml = wr * 64 + mi * 16 + (lane >> 4) * 4 + j;
        const int gm = m0 + ml;
        if (gm >= cnt) continue;
        const int tk = tok_idx[e * TOKENS + gm];
        const float w = tok_w[e * TOKENS + gm];
        float* orow = out + (size_t)tk * DIM;
#pragma unroll
        for (int ni = 0; ni < 4; ++ni) {
          const int d = n0 + wc * 64 + ni * 16 + (lane & 15);
          atomicAdd(orow + d, w * (acc[mi][ni][j] + bias[e * N + d]));
        }
      }
    }
  }
}

// ---------------- fused residual + layernorm (in place on out) ----------------
__global__ void ln_kernel(float* __restrict__ out, const float* __restrict__ gamma,
                          const float* __restrict__ beta) {
  const int lane = threadIdx.x & 63;
  const int wid = threadIdx.x >> 6;
  const int t = blockIdx.x * 4 + wid;
  float* row = out + (size_t)t * DIM;
  float4 v[4];
  const float4* r4 = (const float4*)(row + lane * 16);
#pragma unroll
  for (int i = 0; i < 4; ++i) v[i] = r4[i];
  float s = 0.f, s2 = 0.f;
#pragma unroll
  for (int i = 0; i < 4; ++i) {
    s += v[i].x + v[i].y + v[i].z + v[i].w;
    s2 += v[i].x * v[i].x + v[i].y * v[i].y + v[i].z * v[i].z + v[i].w * v[i].w;
  }
#pragma unroll
  for (int sh = 1; sh < 64; sh <<= 1) {
    s += __shfl_xor(s, sh, 64);
    s2 += __shfl_xor(s2, sh, 64);
  }
  const float mu = s * (1.0f / DIM);
  const float var = s2 * (1.0f / DIM) - mu * mu;
  const float rs = rsqrtf(var + 1e-5f);
  float4* w4 = (float4*)(row + lane * 16);
#pragma unroll
  for (int i = 0; i < 4; ++i) {
    const int d = lane * 16 + i * 4;
    float4 g = *(const float4*)(gamma + d);
    float4 b = *(const float4*)(beta + d);
    float4 o;
    o.x = (v[i].x - mu) * rs * g.x + b.x;
    o.y = (v[i].y - mu) * rs * g.y + b.y;
    o.z = (v[i].z - mu) * rs * g.z + b.z;
    o.w = (v[i].w - mu) * rs * g.w + b.w;
    w4[i] = o;
  }
}

extern "C" void kernel_launch(void* const* d_in, const int* in_sizes, int n_in,
                              void* d_out, int out_size, void* d_ws, size_t ws_size,
                              hipStream_t stream) {
  const float* hs    = (const float*)d_in[0];
  const float* in_t  = (const float*)d_in[1];
  const float* gw    = (const float*)d_in[2];
  const float* gb    = (const float*)d_in[3];
  const float* w1    = (const float*)d_in[4];
  const float* b1    = (const float*)d_in[5];
  const float* w2    = (const float*)d_in[6];
  const float* b2    = (const float*)d_in[7];
  const float* gamma = (const float*)d_in[8];
  const float* beta  = (const float*)d_in[9];
  float* out = (float*)d_out;
  char* ws = (char*)d_ws;

  int* counts = (int*)(ws + 0);
  int* offs = (int*)(ws + 256);
  int* tok_idx = (int*)(ws + 1024);
  float* tok_w = (float*)(ws + 1024 + 262144);
  unsigned short* hs_bf = (unsigned short*)(ws + 525312);
  unsigned short* w1t = (unsigned short*)(ws + 17302528);   // [E][F][D] bf16
  unsigned short* w2t = (unsigned short*)(ws + 84411392);   // [E][D][F] bf16
  unsigned short* h_buf = (unsigned short*)(ws + 151520256); // [2*TOKENS][F] bf16

  zero_counts_kernel<<<1, 64, 0, stream>>>(counts);
  router_kernel<<<TOKENS / 4, 256, 0, stream>>>(hs, gw, gb, counts, tok_idx, tok_w, hs_bf);
  scan_kernel<<<1, 64, 0, stream>>>(counts, offs);
  cast_transpose_kernel<<<dim3(FDIM / 64, DIM / 64, NEXP), 256, 0, stream>>>(w1, w1t, DIM, FDIM);
  cast_transpose_kernel<<<dim3(DIM / 64, FDIM / 64, NEXP), 256, 0, stream>>>(w2, w2t, FDIM, DIM);
  copy_kernel<<<2048, 256, 0, stream>>>(out, in_t, TOKENS * DIM / 4);
  moe_gemm<0, DIM, FDIM><<<dim3(FDIM / 128, TOKENS / 128, NEXP), 256, 0, stream>>>(
      hs_bf, w1t, b1, counts, offs, tok_idx, tok_w, h_buf, nullptr);
  moe_gemm<1, FDIM, DIM><<<dim3(DIM / 128, TOKENS / 128, NEXP), 256, 0, stream>>>(
      h_buf, w2t, b2, counts, offs, tok_idx, tok_w, nullptr, out);
  ln_kernel<<<TOKENS / 4, 256, 0, stream>>>(out, gamma, beta);
}

// Round 2
// 920.429 us; speedup vs baseline: 1.1169x; 1.1169x over previous
//
#include <hip/hip_runtime.h>

#define TOKENS 8192
#define DIM 1024
#define NEXP 8
#define FDIM 4096

typedef __bf16 bf16x8 __attribute__((ext_vector_type(8)));
typedef float f32x4 __attribute__((ext_vector_type(4)));

__device__ __forceinline__ unsigned short f2bf(float f) {
  unsigned u = __builtin_bit_cast(unsigned, f);
  u += 0x7fffu + ((u >> 16) & 1u);
  return (unsigned short)(u >> 16);
}

__device__ __forceinline__ float bf2f(unsigned short s) {
  unsigned u = (unsigned)s << 16;
  return __builtin_bit_cast(float, u);
}

__device__ __forceinline__ void gload16(const void* g, void* l) {
  __builtin_amdgcn_global_load_lds(
      (const __attribute__((address_space(1))) unsigned int*)g,
      (__attribute__((address_space(3))) unsigned int*)l, 16, 0, 0);
}

// ---------------- router ----------------
__global__ void zero_counts_kernel(int* counts) {
  if (threadIdx.x < NEXP) counts[threadIdx.x] = 0;
}

__global__ void scan_kernel(const int* counts, int* offs) {
  if (threadIdx.x == 0) {
    int s = 0;
    for (int e = 0; e < NEXP; ++e) { offs[e] = s; s += counts[e]; }
    offs[NEXP] = s;
  }
}

__global__ void router_kernel(const float* __restrict__ hs,
                              const float* __restrict__ gw,
                              const float* __restrict__ gb,
                              int* __restrict__ counts,
                              int* __restrict__ tok_idx,
                              float* __restrict__ tok_w,
                              unsigned int* __restrict__ slotinfo,
                              unsigned short* __restrict__ hs_bf) {
  const int lane = threadIdx.x & 63;
  const int wid = threadIdx.x >> 6;
  const int t = blockIdx.x * 4 + wid;
  const float* row = hs + (size_t)t * DIM;

  float x[16];
  const float4* r4 = (const float4*)(row + lane * 16);
#pragma unroll
  for (int i = 0; i < 4; ++i) {
    float4 v = r4[i];
    x[i * 4 + 0] = v.x; x[i * 4 + 1] = v.y; x[i * 4 + 2] = v.z; x[i * 4 + 3] = v.w;
  }

  float acc[8];
#pragma unroll
  for (int e = 0; e < 8; ++e) acc[e] = 0.f;
#pragma unroll
  for (int i = 0; i < 16; ++i) {
    const int d = lane * 16 + i;
    const float4* g4 = (const float4*)(gw + (size_t)d * 8);
    float4 g0 = g4[0], g1 = g4[1];
    const float xv = x[i];
    acc[0] += xv * g0.x; acc[1] += xv * g0.y; acc[2] += xv * g0.z; acc[3] += xv * g0.w;
    acc[4] += xv * g1.x; acc[5] += xv * g1.y; acc[6] += xv * g1.z; acc[7] += xv * g1.w;
  }
#pragma unroll
  for (int sh = 1; sh < 64; sh <<= 1) {
#pragma unroll
    for (int e = 0; e < 8; ++e) acc[e] += __shfl_xor(acc[e], sh, 64);
  }
#pragma unroll
  for (int e = 0; e < 8; ++e) acc[e] += gb[e];

  float mx = acc[0];
#pragma unroll
  for (int e = 1; e < 8; ++e) mx = fmaxf(mx, acc[e]);
  float p[8];
  float sum = 0.f;
#pragma unroll
  for (int e = 0; e < 8; ++e) { p[e] = __expf(acc[e] - mx); sum += p[e]; }
  const float inv = 1.0f / sum;

  int i0 = 0; float b0 = p[0];
#pragma unroll
  for (int e = 1; e < 8; ++e) if (p[e] > b0) { b0 = p[e]; i0 = e; }
  int i1 = -1; float b1v = -1.f;
#pragma unroll
  for (int e = 0; e < 8; ++e) if (e != i0 && p[e] > b1v) { b1v = p[e]; i1 = e; }

  if (lane == 0) {
    int pos0 = atomicAdd(&counts[i0], 1);
    tok_idx[i0 * TOKENS + pos0] = t;
    tok_w[i0 * TOKENS + pos0] = b0 * inv;
    slotinfo[t * 2 + 0] = ((unsigned)i0 << 13) | (unsigned)pos0;
    int pos1 = atomicAdd(&counts[i1], 1);
    tok_idx[i1 * TOKENS + pos1] = t;
    tok_w[i1 * TOKENS + pos1] = b1v * inv;
    slotinfo[t * 2 + 1] = ((unsigned)i1 << 13) | (unsigned)pos1;
  }

  unsigned short us[16];
#pragma unroll
  for (int i = 0; i < 16; ++i) us[i] = f2bf(x[i]);
  uint4 o0, o1;
  o0.x = (unsigned)us[0] | ((unsigned)us[1] << 16);
  o0.y = (unsigned)us[2] | ((unsigned)us[3] << 16);
  o0.z = (unsigned)us[4] | ((unsigned)us[5] << 16);
  o0.w = (unsigned)us[6] | ((unsigned)us[7] << 16);
  o1.x = (unsigned)us[8] | ((unsigned)us[9] << 16);
  o1.y = (unsigned)us[10] | ((unsigned)us[11] << 16);
  o1.z = (unsigned)us[12] | ((unsigned)us[13] << 16);
  o1.w = (unsigned)us[14] | ((unsigned)us[15] << 16);
  uint4* dst = (uint4*)(hs_bf + (size_t)t * DIM + lane * 16);
  dst[0] = o0;
  dst[1] = o1;
}

// ---------------- transpose + cast weights: src[e][R][C] f32 -> dst[e][C][R] bf16 ----------------
__global__ void cast_transpose_kernel(const float* __restrict__ src,
                                      unsigned short* __restrict__ dst,
                                      int R, int C) {
  __shared__ float tile[64][65];
  const int e = blockIdx.z;
  const int r0 = blockIdx.y * 64;
  const int c0 = blockIdx.x * 64;
  const float* s = src + (size_t)e * R * C;
  unsigned int* d = (unsigned int*)(dst + (size_t)e * R * C);

#pragma unroll
  for (int i = 0; i < 16; ++i) {
    const int idx = threadIdx.x + i * 256;
    const int r = idx >> 6;
    const int c = idx & 63;
    tile[r][c] = s[(size_t)(r0 + r) * C + (c0 + c)];
  }
  __syncthreads();
#pragma unroll
  for (int i = 0; i < 8; ++i) {
    const int idx = threadIdx.x + i * 256;
    const int c = idx >> 5;
    const int r = (idx & 31) * 2;
    unsigned pk = (unsigned)f2bf(tile[r][c]) | ((unsigned)f2bf(tile[r + 1][c]) << 16);
    d[((size_t)(c0 + c) * R + (r0 + r)) >> 1] = pk;
  }
}

// ---------------- grouped GEMM ----------------
// MODE 0: h_buf[goff+pos] = gelu(gather(hs_bf) @ w1t^T + b1)   (K=1024, N=4096)
// MODE 1: y_buf[goff+pos]  =        h_buf       @ w2t^T + b2   (K=4096, N=1024)
template<int MODE, int K, int N>
__global__ __launch_bounds__(256)
void moe_gemm(const unsigned short* __restrict__ Abase,
              const unsigned short* __restrict__ Bbase,
              const float* __restrict__ bias,
              const int* __restrict__ counts,
              const int* __restrict__ offs,
              const int* __restrict__ tok_idx,
              unsigned short* __restrict__ dst) {
  constexpr int BM = 128, BN = 128, BK = 64;
  __shared__ __align__(16) unsigned char sm[(BM + BN) * BK * 2];
  unsigned char* As = sm;
  unsigned char* Bs = sm + BM * BK * 2;

  const int e = blockIdx.z;
  const int cnt = counts[e];
  const int m0 = blockIdx.y * BM;
  if (m0 >= cnt) return;
  const int n0 = blockIdx.x * BN;
  const int goff = offs[e];

  const int tid = threadIdx.x;
  const int lane = tid & 63;
  const int wid = tid >> 6;
  const int wr = wid >> 1;
  const int wc = wid & 1;

  const unsigned char* a_src[4];
  const unsigned char* b_src[4];
  unsigned char* a_dst[4];
  unsigned char* b_dst[4];
  const unsigned char* Bexp = (const unsigned char*)(Bbase + (size_t)e * K * N);

#pragma unroll
  for (int j = 0; j < 4; ++j) {
    const int row = wid * 32 + j * 8 + (lane >> 3);
    const int ch = (lane & 7) ^ (row & 7);  // source pre-swizzle for conflict-free ds_read
    const int gm = m0 + row;
    const int gmc = gm < cnt ? gm : cnt - 1;
    size_t arow;
    if (MODE == 0) {
      arow = (size_t)tok_idx[e * TOKENS + gmc] * K;
    } else {
      arow = (size_t)(goff + gmc) * K;
    }
    a_src[j] = (const unsigned char*)(Abase + arow) + ch * 16;
    b_src[j] = Bexp + (size_t)(n0 + row) * (K * 2) + ch * 16;
    a_dst[j] = As + (wid * 32 + j * 8) * (BK * 2);
    b_dst[j] = Bs + (wid * 32 + j * 8) * (BK * 2);
  }

  // hoisted fragment LDS byte-offsets (loop-invariant; keep in VGPRs,
  // static-indexed so they never spill to scratch)
  unsigned aoff[2][4], boff[2][4];
#pragma unroll
  for (int kk = 0; kk < 2; ++kk) {
#pragma unroll
    for (int i = 0; i < 4; ++i) {
      const int ra = wr * 64 + i * 16 + (lane & 15);
      aoff[kk][i] = ra * 128 + (((kk * 4 + (lane >> 4)) ^ (ra & 7)) * 16);
      const int rb = wc * 64 + i * 16 + (lane & 15);
      boff[kk][i] = rb * 128 + (((kk * 4 + (lane >> 4)) ^ (rb & 7)) * 16);
    }
  }

  f32x4 acc[4][4];
  const f32x4 fz = {0.f, 0.f, 0.f, 0.f};
#pragma unroll
  for (int mi = 0; mi < 4; ++mi)
#pragma unroll
    for (int ni = 0; ni < 4; ++ni) acc[mi][ni] = fz;

  for (int kt = 0; kt < K / BK; ++kt) {
    const int kb = kt * (BK * 2);
#pragma unroll
    for (int j = 0; j < 4; ++j) gload16(a_src[j] + kb, a_dst[j]);
#pragma unroll
    for (int j = 0; j < 4; ++j) gload16(b_src[j] + kb, b_dst[j]);
    __syncthreads();
#pragma unroll
    for (int kk = 0; kk < 2; ++kk) {
      bf16x8 af[4], bfr[4];
#pragma unroll
      for (int mi = 0; mi < 4; ++mi) af[mi] = *(const bf16x8*)(As + aoff[kk][mi]);
#pragma unroll
      for (int ni = 0; ni < 4; ++ni) bfr[ni] = *(const bf16x8*)(Bs + boff[kk][ni]);
#pragma unroll
      for (int mi = 0; mi < 4; ++mi)
#pragma unroll
        for (int ni = 0; ni < 4; ++ni)
          acc[mi][ni] = __builtin_amdgcn_mfma_f32_16x16x32_bf16(af[mi], bfr[ni], acc[mi][ni], 0, 0, 0);
    }
    __syncthreads();
  }

  // epilogue: bias (+gelu for MODE 0), write bf16 rows [goff+gm][N]
#pragma unroll
  for (int ni = 0; ni < 4; ++ni) {
    const int f = n0 + wc * 64 + ni * 16 + (lane & 15);
    const float bv = bias[e * N + f];
#pragma unroll
    for (int mi = 0; mi < 4; ++mi) {
#pragma unroll
      for (int j = 0; j < 4; ++j) {
        const int ml = wr * 64 + mi * 16 + (lane >> 4) * 4 + j;
        const int gm = m0 + ml;
        if (gm < cnt) {
          float v = acc[mi][ni][j] + bv;
          if (MODE == 0) {
            // tanh-gelu via hw exp: tanh(u) = 1 - 2/(1+e^{2u})
            const float u = 0.7978845608028654f * (v + 0.044715f * v * v * v);
            const float t = 1.0f - 2.0f / (1.0f + __expf(2.0f * u));
            v = 0.5f * v * (1.0f + t);
          }
          dst[(size_t)(goff + gm) * N + f] = f2bf(v);
        }
      }
    }
  }
}

// ---------------- fused combine + residual + layernorm ----------------
__global__ void ln_combine_kernel(const unsigned short* __restrict__ y_buf,
                                  const float* __restrict__ in_t,
                                  const int* __restrict__ offs,
                                  const unsigned int* __restrict__ slotinfo,
                                  const float* __restrict__ tok_w,
                                  const float* __restrict__ gamma,
                                  const float* __restrict__ beta,
                                  float* __restrict__ out) {
  const int lane = threadIdx.x & 63;
  const int wid = threadIdx.x >> 6;
  const int t = blockIdx.x * 4 + wid;

  const unsigned s0 = slotinfo[t * 2 + 0];
  const unsigned s1 = slotinfo[t * 2 + 1];
  const int e0 = s0 >> 13, p0 = s0 & 8191;
  const int e1 = s1 >> 13, p1 = s1 & 8191;
  const float w0 = tok_w[e0 * TOKENS + p0];
  const float w1 = tok_w[e1 * TOKENS + p1];
  const size_t r0 = (size_t)(offs[e0] + p0) * DIM;
  const size_t r1 = (size_t)(offs[e1] + p1) * DIM;

  float v[16];
  {
    const float4* i4 = (const float4*)(in_t + (size_t)t * DIM + lane * 16);
    const uint4* y0 = (const uint4*)(y_buf + r0 + lane * 16);
    const uint4* y1 = (const uint4*)(y_buf + r1 + lane * 16);
#pragma unroll
    for (int i = 0; i < 4; ++i) {
      float4 a = i4[i];
      v[i * 4 + 0] = a.x; v[i * 4 + 1] = a.y; v[i * 4 + 2] = a.z; v[i * 4 + 3] = a.w;
    }
#pragma unroll
    for (int i = 0; i < 2; ++i) {
      uint4 u0 = y0[i];
      uint4 u1 = y1[i];
      const unsigned uw0[4] = {u0.x, u0.y, u0.z, u0.w};
      const unsigned uw1[4] = {u1.x, u1.y, u1.z, u1.w};
#pragma unroll
      for (int k = 0; k < 4; ++k) {
        const int base = i * 8 + k * 2;
        v[base + 0] += w0 * bf2f((unsigned short)(uw0[k] & 0xffff)) +
                       w1 * bf2f((unsigned short)(uw1[k] & 0xffff));
        v[base + 1] += w0 * bf2f((unsigned short)(uw0[k] >> 16)) +
                       w1 * bf2f((unsigned short)(uw1[k] >> 16));
      }
    }
  }

  float s = 0.f, s2 = 0.f;
#pragma unroll
  for (int i = 0; i < 16; ++i) { s += v[i]; s2 += v[i] * v[i]; }
#pragma unroll
  for (int sh = 1; sh < 64; sh <<= 1) {
    s += __shfl_xor(s, sh, 64);
    s2 += __shfl_xor(s2, sh, 64);
  }
  const float mu = s * (1.0f / DIM);
  const float var = s2 * (1.0f / DIM) - mu * mu;
  const float rs = rsqrtf(var + 1e-5f);

  float4* w4 = (float4*)(out + (size_t)t * DIM + lane * 16);
#pragma unroll
  for (int i = 0; i < 4; ++i) {
    const int d = lane * 16 + i * 4;
    float4 g = *(const float4*)(gamma + d);
    float4 b = *(const float4*)(beta + d);
    float4 o;
    o.x = (v[i * 4 + 0] - mu) * rs * g.x + b.x;
    o.y = (v[i * 4 + 1] - mu) * rs * g.y + b.y;
    o.z = (v[i * 4 + 2] - mu) * rs * g.z + b.z;
    o.w = (v[i * 4 + 3] - mu) * rs * g.w + b.w;
    w4[i] = o;
  }
}

extern "C" void kernel_launch(void* const* d_in, const int* in_sizes, int n_in,
                              void* d_out, int out_size, void* d_ws, size_t ws_size,
                              hipStream_t stream) {
  const float* hs    = (const float*)d_in[0];
  const float* in_t  = (const float*)d_in[1];
  const float* gw    = (const float*)d_in[2];
  const float* gb    = (const float*)d_in[3];
  const float* w1    = (const float*)d_in[4];
  const float* b1    = (const float*)d_in[5];
  const float* w2    = (const float*)d_in[6];
  const float* b2    = (const float*)d_in[7];
  const float* gamma = (const float*)d_in[8];
  const float* beta  = (const float*)d_in[9];
  float* out = (float*)d_out;
  char* ws = (char*)d_ws;

  // workspace layout (bytes)
  int* counts            = (int*)(ws + 0);                    // 32
  int* offs              = (int*)(ws + 256);                  // 36
  unsigned int* slotinfo = (unsigned int*)(ws + 512);         // 64 KiB
  int* tok_idx           = (int*)(ws + 66048);                // 256 KiB
  float* tok_w           = (float*)(ws + 328192);             // 256 KiB
  unsigned short* hs_bf  = (unsigned short*)(ws + 590336);    // 16 MiB
  unsigned short* w1t    = (unsigned short*)(ws + 17367552);  // 64 MiB [E][F][D]
  unsigned short* w2t    = (unsigned short*)(ws + 84476416);  // 64 MiB [E][D][F]
  unsigned short* h_buf  = (unsigned short*)(ws + 151585280); // 128 MiB [2T][F]
  // y_buf aliases hs_bf + head of w1t: both are fully rewritten every call
  // before any reader; y_buf is written (MODE1) strictly after w1t/hs_bf's
  // last reader (MODE0) on the same stream.
  unsigned short* y_buf  = (unsigned short*)(ws + 590336);    // 32 MiB [2T][D]

  zero_counts_kernel<<<1, 64, 0, stream>>>(counts);
  router_kernel<<<TOKENS / 4, 256, 0, stream>>>(hs, gw, gb, counts, tok_idx, tok_w,
                                                slotinfo, hs_bf);
  scan_kernel<<<1, 64, 0, stream>>>(counts, offs);
  cast_transpose_kernel<<<dim3(FDIM / 64, DIM / 64, NEXP), 256, 0, stream>>>(w1, w1t, DIM, FDIM);
  cast_transpose_kernel<<<dim3(DIM / 64, FDIM / 64, NEXP), 256, 0, stream>>>(w2, w2t, FDIM, DIM);
  moe_gemm<0, DIM, FDIM><<<dim3(FDIM / 128, TOKENS / 128, NEXP), 256, 0, stream>>>(
      hs_bf, w1t, b1, counts, offs, tok_idx, h_buf);
  moe_gemm<1, FDIM, DIM><<<dim3(DIM / 128, TOKENS / 128, NEXP), 256, 0, stream>>>(
      h_buf, w2t, b2, counts, offs, tok_idx, y_buf);
  ln_combine_kernel<<<TOKENS / 4, 256, 0, stream>>>(y_buf, in_t, offs, slotinfo,
                                                    tok_w, gamma, beta, out);
}

// Round 3
// 798.297 us; speedup vs baseline: 1.2877x; 1.1530x over previous
//
#include <hip/hip_runtime.h>

#define TOKENS 8192
#define DIM 1024
#define NEXP 8
#define FDIM 4096

typedef __bf16 bf16x8 __attribute__((ext_vector_type(8)));
typedef float f32x4 __attribute__((ext_vector_type(4)));

__device__ __forceinline__ unsigned short f2bf(float f) {
  unsigned u = __builtin_bit_cast(unsigned, f);
  u += 0x7fffu + ((u >> 16) & 1u);
  return (unsigned short)(u >> 16);
}

__device__ __forceinline__ float bf2f(unsigned short s) {
  unsigned u = (unsigned)s << 16;
  return __builtin_bit_cast(float, u);
}

__device__ __forceinline__ void gload16(const void* g, void* l) {
  __builtin_amdgcn_global_load_lds(
      (const __attribute__((address_space(1))) unsigned int*)g,
      (__attribute__((address_space(3))) unsigned int*)l, 16, 0, 0);
}

// ---------------- router ----------------
__global__ void zero_counts_kernel(int* counts) {
  if (threadIdx.x < NEXP) counts[threadIdx.x] = 0;
}

__global__ void scan_kernel(const int* counts, int* offs) {
  if (threadIdx.x == 0) {
    int s = 0;
    for (int e = 0; e < NEXP; ++e) { offs[e] = s; s += counts[e]; }
    offs[NEXP] = s;
  }
}

__global__ void router_kernel(const float* __restrict__ hs,
                              const float* __restrict__ gw,
                              const float* __restrict__ gb,
                              int* __restrict__ counts,
                              int* __restrict__ tok_idx,
                              float* __restrict__ tok_w,
                              unsigned int* __restrict__ slotinfo,
                              unsigned short* __restrict__ hs_bf) {
  const int lane = threadIdx.x & 63;
  const int wid = threadIdx.x >> 6;
  const int t = blockIdx.x * 4 + wid;
  const float* row = hs + (size_t)t * DIM;

  float x[16];
  const float4* r4 = (const float4*)(row + lane * 16);
#pragma unroll
  for (int i = 0; i < 4; ++i) {
    float4 v = r4[i];
    x[i * 4 + 0] = v.x; x[i * 4 + 1] = v.y; x[i * 4 + 2] = v.z; x[i * 4 + 3] = v.w;
  }

  float acc[8];
#pragma unroll
  for (int e = 0; e < 8; ++e) acc[e] = 0.f;
#pragma unroll
  for (int i = 0; i < 16; ++i) {
    const int d = lane * 16 + i;
    const float4* g4 = (const float4*)(gw + (size_t)d * 8);
    float4 g0 = g4[0], g1 = g4[1];
    const float xv = x[i];
    acc[0] += xv * g0.x; acc[1] += xv * g0.y; acc[2] += xv * g0.z; acc[3] += xv * g0.w;
    acc[4] += xv * g1.x; acc[5] += xv * g1.y; acc[6] += xv * g1.z; acc[7] += xv * g1.w;
  }
#pragma unroll
  for (int sh = 1; sh < 64; sh <<= 1) {
#pragma unroll
    for (int e = 0; e < 8; ++e) acc[e] += __shfl_xor(acc[e], sh, 64);
  }
#pragma unroll
  for (int e = 0; e < 8; ++e) acc[e] += gb[e];

  float mx = acc[0];
#pragma unroll
  for (int e = 1; e < 8; ++e) mx = fmaxf(mx, acc[e]);
  float p[8];
  float sum = 0.f;
#pragma unroll
  for (int e = 0; e < 8; ++e) { p[e] = __expf(acc[e] - mx); sum += p[e]; }
  const float inv = 1.0f / sum;

  int i0 = 0; float b0 = p[0];
#pragma unroll
  for (int e = 1; e < 8; ++e) if (p[e] > b0) { b0 = p[e]; i0 = e; }
  int i1 = -1; float b1v = -1.f;
#pragma unroll
  for (int e = 0; e < 8; ++e) if (e != i0 && p[e] > b1v) { b1v = p[e]; i1 = e; }

  if (lane == 0) {
    int pos0 = atomicAdd(&counts[i0], 1);
    tok_idx[i0 * TOKENS + pos0] = t;
    tok_w[i0 * TOKENS + pos0] = b0 * inv;
    slotinfo[t * 2 + 0] = ((unsigned)i0 << 13) | (unsigned)pos0;
    int pos1 = atomicAdd(&counts[i1], 1);
    tok_idx[i1 * TOKENS + pos1] = t;
    tok_w[i1 * TOKENS + pos1] = b1v * inv;
    slotinfo[t * 2 + 1] = ((unsigned)i1 << 13) | (unsigned)pos1;
  }

  unsigned short us[16];
#pragma unroll
  for (int i = 0; i < 16; ++i) us[i] = f2bf(x[i]);
  uint4 o0, o1;
  o0.x = (unsigned)us[0] | ((unsigned)us[1] << 16);
  o0.y = (unsigned)us[2] | ((unsigned)us[3] << 16);
  o0.z = (unsigned)us[4] | ((unsigned)us[5] << 16);
  o0.w = (unsigned)us[6] | ((unsigned)us[7] << 16);
  o1.x = (unsigned)us[8] | ((unsigned)us[9] << 16);
  o1.y = (unsigned)us[10] | ((unsigned)us[11] << 16);
  o1.z = (unsigned)us[12] | ((unsigned)us[13] << 16);
  o1.w = (unsigned)us[14] | ((unsigned)us[15] << 16);
  uint4* dst = (uint4*)(hs_bf + (size_t)t * DIM + lane * 16);
  dst[0] = o0;
  dst[1] = o1;
}

// ---------------- transpose + cast weights: src[e][R][C] f32 -> dst[e][C][R] bf16 ----------------
__global__ void cast_transpose_kernel(const float* __restrict__ src,
                                      unsigned short* __restrict__ dst,
                                      int R, int C) {
  __shared__ float tile[64][65];
  const int e = blockIdx.z;
  const int r0 = blockIdx.y * 64;
  const int c0 = blockIdx.x * 64;
  const float* s = src + (size_t)e * R * C;
  unsigned int* d = (unsigned int*)(dst + (size_t)e * R * C);

#pragma unroll
  for (int i = 0; i < 16; ++i) {
    const int idx = threadIdx.x + i * 256;
    const int r = idx >> 6;
    const int c = idx & 63;
    tile[r][c] = s[(size_t)(r0 + r) * C + (c0 + c)];
  }
  __syncthreads();
#pragma unroll
  for (int i = 0; i < 8; ++i) {
    const int idx = threadIdx.x + i * 256;
    const int c = idx >> 5;
    const int r = (idx & 31) * 2;
    unsigned pk = (unsigned)f2bf(tile[r][c]) | ((unsigned)f2bf(tile[r + 1][c]) << 16);
    d[((size_t)(c0 + c) * R + (r0 + r)) >> 1] = pk;
  }
}

// ---------------- grouped GEMM: 256x256 tile, BK=32, 4-deep LDS ring, counted vmcnt ----------------
// MODE 0: h_buf[goff+pos] = gelu(gather(hs_bf) @ w1t^T + b1)   (K=1024, N=4096)
// MODE 1: y_buf[goff+pos] =        h_buf       @ w2t^T + b2    (K=4096, N=1024)
//
// LDS ring: A slots 0..3 at s*16384 (each 256 rows x 64B), B slots at 65536 + s*16384.
// Tile t uses slot t&3; tile t+3 staged into slot (t+3)&3 == (t-1)&3 (free since t-1's
// trailing barrier). One vmcnt(8) gate per K-tile guarantees tile t+1 landed (tiles
// t+2,t+3 = 8 newest loads may remain in flight). Tail peels gates 8 -> 4 -> 0.

#define GEMM_KTILE(sb, sbW, DO_ISSUE, ...)                                          \
  {                                                                                 \
    bf16x8 a0_[4], b0_[4];                                                          \
    _Pragma("unroll") for (int f_ = 0; f_ < 4; ++f_)                                \
      a0_[f_] = *(const bf16x8*)(sm + (sb) + aoff[f_]);                             \
    _Pragma("unroll") for (int g_ = 0; g_ < 4; ++g_)                                \
      b0_[g_] = *(const bf16x8*)(sm + 65536 + (sb) + boff[g_]);                     \
    if (DO_ISSUE) {                                                                 \
      gload16(aS0, sm + (sbW) + wdst);                                              \
      gload16(aS1, sm + (sbW) + 8192 + wdst);                                       \
      aS0 += 64; aS1 += 64;                                                         \
    }                                                                               \
    __builtin_amdgcn_sched_barrier(0);                                              \
    __builtin_amdgcn_s_barrier();                                                   \
    asm volatile("s_waitcnt lgkmcnt(0)" ::: "memory");                              \
    __builtin_amdgcn_sched_barrier(0);                                              \
    __builtin_amdgcn_s_setprio(1);                                                  \
    _Pragma("unroll") for (int f_ = 0; f_ < 4; ++f_)                                \
      _Pragma("unroll") for (int g_ = 0; g_ < 4; ++g_)                              \
        acc[f_][g_] = __builtin_amdgcn_mfma_f32_16x16x32_bf16(                      \
            a0_[f_], b0_[g_], acc[f_][g_], 0, 0, 0);                                \
    __builtin_amdgcn_s_setprio(0);                                                  \
    __builtin_amdgcn_sched_barrier(0);                                              \
    __builtin_amdgcn_s_barrier();                                                   \
    bf16x8 a1_[4];                                                                  \
    _Pragma("unroll") for (int f_ = 0; f_ < 4; ++f_)                                \
      a1_[f_] = *(const bf16x8*)(sm + (sb) + aoff[4 + f_]);                         \
    if (DO_ISSUE) {                                                                 \
      gload16(bS0, sm + 65536 + (sbW) + wdst);                                      \
      gload16(bS1, sm + 65536 + (sbW) + 8192 + wdst);                               \
      bS0 += 64; bS1 += 64;                                                         \
    }                                                                               \
    __VA_ARGS__;                                                                    \
    __builtin_amdgcn_sched_barrier(0);                                              \
    __builtin_amdgcn_s_barrier();                                                   \
    asm volatile("s_waitcnt lgkmcnt(0)" ::: "memory");                              \
    __builtin_amdgcn_sched_barrier(0);                                              \
    __builtin_amdgcn_s_setprio(1);                                                  \
    _Pragma("unroll") for (int f_ = 0; f_ < 4; ++f_)                                \
      _Pragma("unroll") for (int g_ = 0; g_ < 4; ++g_)                              \
        acc[4 + f_][g_] = __builtin_amdgcn_mfma_f32_16x16x32_bf16(                  \
            a1_[f_], b0_[g_], acc[4 + f_][g_], 0, 0, 0);                            \
    __builtin_amdgcn_s_setprio(0);                                                  \
    __builtin_amdgcn_sched_barrier(0);                                              \
    __builtin_amdgcn_s_barrier();                                                   \
  }

template<int MODE, int K, int N>
__global__ __launch_bounds__(512, 2)
void moe_gemm(const unsigned short* __restrict__ Abase,
              const unsigned short* __restrict__ Bbase,
              const float* __restrict__ bias,
              const int* __restrict__ counts,
              const int* __restrict__ offs,
              const int* __restrict__ tok_idx,
              unsigned short* __restrict__ dst) {
  constexpr int NT = K / 32;  // K-tiles (>= 4)
  __shared__ __align__(16) unsigned char sm[131072];

  const int e = blockIdx.z;
  const int cnt = counts[e];
  const int m0 = blockIdx.y * 256;
  if (m0 >= cnt) return;
  const int n0 = blockIdx.x * 256;
  const int goff = offs[e];

  const int tid = threadIdx.x;
  const int lane = tid & 63;
  const int wid = tid >> 6;
  const int wr = wid >> 2;   // 0..1 : M band (128 rows)
  const int wcn = wid & 3;   // 0..3 : N band (64 cols)
  const int l15 = lane & 15;
  const int cg = lane >> 4;  // 0..3 : 16B chunk group within 64B row
  const int wdst = wid * 1024;

  // ---- staging source addresses (per thread: rows urow and urow+128) ----
  const int urow = tid >> 2;
  const int uchk = tid & 3;
  const int swz = uchk ^ ((urow >> 1) & 3);  // same for urow+128
  const unsigned char* Bexp = (const unsigned char*)(Bbase + (size_t)e * K * N);

  int gA0 = m0 + urow;       if (gA0 > cnt - 1) gA0 = cnt - 1;
  int gA1 = m0 + urow + 128; if (gA1 > cnt - 1) gA1 = cnt - 1;
  size_t rowA0, rowA1;
  if (MODE == 0) {
    rowA0 = (size_t)tok_idx[e * TOKENS + gA0] * K;
    rowA1 = (size_t)tok_idx[e * TOKENS + gA1] * K;
  } else {
    rowA0 = (size_t)(goff + gA0) * K;
    rowA1 = (size_t)(goff + gA1) * K;
  }
  const unsigned char* aS0 = (const unsigned char*)(Abase + rowA0) + swz * 16;
  const unsigned char* aS1 = (const unsigned char*)(Abase + rowA1) + swz * 16;
  const unsigned char* bS0 = Bexp + (size_t)(n0 + urow) * (K * 2) + swz * 16;
  const unsigned char* bS1 = Bexp + (size_t)(n0 + urow + 128) * (K * 2) + swz * 16;

  // ---- ds_read fragment byte offsets (loop-invariant, slot base added per tile) ----
  int aoff[8], boff[4];
#pragma unroll
  for (int f = 0; f < 8; ++f) {
    const int r = wr * 128 + f * 16 + l15;
    aoff[f] = r * 64 + ((cg ^ ((r >> 1) & 3)) * 16);
  }
#pragma unroll
  for (int g = 0; g < 4; ++g) {
    const int r = wcn * 64 + g * 16 + l15;
    boff[g] = r * 64 + ((cg ^ ((r >> 1) & 3)) * 16);
  }

  f32x4 acc[8][4];
  const f32x4 fz = {0.f, 0.f, 0.f, 0.f};
#pragma unroll
  for (int f = 0; f < 8; ++f)
#pragma unroll
    for (int g = 0; g < 4; ++g) acc[f][g] = fz;

  // ---- prologue: stage K-tiles 0,1,2 ----
#pragma unroll
  for (int j = 0; j < 3; ++j) {
    gload16(aS0, sm + j * 16384 + wdst);
    gload16(aS1, sm + j * 16384 + 8192 + wdst);
    gload16(bS0, sm + 65536 + j * 16384 + wdst);
    gload16(bS1, sm + 65536 + j * 16384 + 8192 + wdst);
    aS0 += 64; aS1 += 64; bS0 += 64; bS1 += 64;
  }
  asm volatile("s_waitcnt vmcnt(8)" ::: "memory");  // tile 0 landed
  __builtin_amdgcn_sched_barrier(0);
  __builtin_amdgcn_s_barrier();

  // ---- main loop ----
#pragma unroll 1
  for (int t = 0; t < NT - 3; ++t) {
    const int sb = (t & 3) * 16384;
    const int sbW = ((t + 3) & 3) * 16384;
    GEMM_KTILE(sb, sbW, true, asm volatile("s_waitcnt vmcnt(8)" ::: "memory"));
  }
  // tail: t = NT-3, NT-2, NT-1 (no more staging)
  GEMM_KTILE(((NT - 3) & 3) * 16384, 0, false,
             asm volatile("s_waitcnt vmcnt(4)" ::: "memory"));
  GEMM_KTILE(((NT - 2) & 3) * 16384, 0, false,
             asm volatile("s_waitcnt vmcnt(0)" ::: "memory"));
  GEMM_KTILE(((NT - 1) & 3) * 16384, 0, false, ((void)0));

  // ---- epilogue ----
#pragma unroll
  for (int g = 0; g < 4; ++g) {
    const int fcol = n0 + wcn * 64 + g * 16 + l15;
    const float bv = bias[e * N + fcol];
#pragma unroll
    for (int f = 0; f < 8; ++f) {
#pragma unroll
      for (int j = 0; j < 4; ++j) {
        const int ml = wr * 128 + f * 16 + cg * 4 + j;
        const int gm = m0 + ml;
        if (gm < cnt) {
          float v = acc[f][g][j] + bv;
          if (MODE == 0) {
            const float u = 0.7978845608028654f * (v + 0.044715f * v * v * v);
            const float th = 1.0f - 2.0f / (1.0f + __expf(2.0f * u));
            v = 0.5f * v * (1.0f + th);
          }
          dst[(size_t)(goff + gm) * N + fcol] = f2bf(v);
        }
      }
    }
  }
}

// ---------------- fused combine + residual + layernorm ----------------
__global__ void ln_combine_kernel(const unsigned short* __restrict__ y_buf,
                                  const float* __restrict__ in_t,
                                  const int* __restrict__ offs,
                                  const unsigned int* __restrict__ slotinfo,
                                  const float* __restrict__ tok_w,
                                  const float* __restrict__ gamma,
                                  const float* __restrict__ beta,
                                  float* __restrict__ out) {
  const int lane = threadIdx.x & 63;
  const int wid = threadIdx.x >> 6;
  const int t = blockIdx.x * 4 + wid;

  const unsigned s0 = slotinfo[t * 2 + 0];
  const unsigned s1 = slotinfo[t * 2 + 1];
  const int e0 = s0 >> 13, p0 = s0 & 8191;
  const int e1 = s1 >> 13, p1 = s1 & 8191;
  const float w0 = tok_w[e0 * TOKENS + p0];
  const float w1 = tok_w[e1 * TOKENS + p1];
  const size_t r0 = (size_t)(offs[e0] + p0) * DIM;
  const size_t r1 = (size_t)(offs[e1] + p1) * DIM;

  float v[16];
  {
    const float4* i4 = (const float4*)(in_t + (size_t)t * DIM + lane * 16);
    const uint4* y0 = (const uint4*)(y_buf + r0 + lane * 16);
    const uint4* y1 = (const uint4*)(y_buf + r1 + lane * 16);
#pragma unroll
    for (int i = 0; i < 4; ++i) {
      float4 a = i4[i];
      v[i * 4 + 0] = a.x; v[i * 4 + 1] = a.y; v[i * 4 + 2] = a.z; v[i * 4 + 3] = a.w;
    }
#pragma unroll
    for (int i = 0; i < 2; ++i) {
      uint4 u0 = y0[i];
      uint4 u1 = y1[i];
      const unsigned uw0[4] = {u0.x, u0.y, u0.z, u0.w};
      const unsigned uw1[4] = {u1.x, u1.y, u1.z, u1.w};
#pragma unroll
      for (int k = 0; k < 4; ++k) {
        const int base = i * 8 + k * 2;
        v[base + 0] += w0 * bf2f((unsigned short)(uw0[k] & 0xffff)) +
                       w1 * bf2f((unsigned short)(uw1[k] & 0xffff));
        v[base + 1] += w0 * bf2f((unsigned short)(uw0[k] >> 16)) +
                       w1 * bf2f((unsigned short)(uw1[k] >> 16));
      }
    }
  }

  float s = 0.f, s2 = 0.f;
#pragma unroll
  for (int i = 0; i < 16; ++i) { s += v[i]; s2 += v[i] * v[i]; }
#pragma unroll
  for (int sh = 1; sh < 64; sh <<= 1) {
    s += __shfl_xor(s, sh, 64);
    s2 += __shfl_xor(s2, sh, 64);
  }
  const float mu = s * (1.0f / DIM);
  const float var = s2 * (1.0f / DIM) - mu * mu;
  const float rs = rsqrtf(var + 1e-5f);

  float4* w4 = (float4*)(out + (size_t)t * DIM + lane * 16);
#pragma unroll
  for (int i = 0; i < 4; ++i) {
    const int d = lane * 16 + i * 4;
    float4 g = *(const float4*)(gamma + d);
    float4 b = *(const float4*)(beta + d);
    float4 o;
    o.x = (v[i * 4 + 0] - mu) * rs * g.x + b.x;
    o.y = (v[i * 4 + 1] - mu) * rs * g.y + b.y;
    o.z = (v[i * 4 + 2] - mu) * rs * g.z + b.z;
    o.w = (v[i * 4 + 3] - mu) * rs * g.w + b.w;
    w4[i] = o;
  }
}

extern "C" void kernel_launch(void* const* d_in, const int* in_sizes, int n_in,
                              void* d_out, int out_size, void* d_ws, size_t ws_size,
                              hipStream_t stream) {
  const float* hs    = (const float*)d_in[0];
  const float* in_t  = (const float*)d_in[1];
  const float* gw    = (const float*)d_in[2];
  const float* gb    = (const float*)d_in[3];
  const float* w1    = (const float*)d_in[4];
  const float* b1    = (const float*)d_in[5];
  const float* w2    = (const float*)d_in[6];
  const float* b2    = (const float*)d_in[7];
  const float* gamma = (const float*)d_in[8];
  const float* beta  = (const float*)d_in[9];
  float* out = (float*)d_out;
  char* ws = (char*)d_ws;

  // workspace layout (bytes)
  int* counts            = (int*)(ws + 0);                    // 32
  int* offs              = (int*)(ws + 256);                  // 36
  unsigned int* slotinfo = (unsigned int*)(ws + 512);         // 64 KiB
  int* tok_idx           = (int*)(ws + 66048);                // 256 KiB
  float* tok_w           = (float*)(ws + 328192);             // 256 KiB
  unsigned short* hs_bf  = (unsigned short*)(ws + 590336);    // 16 MiB
  unsigned short* w1t    = (unsigned short*)(ws + 17367552);  // 64 MiB [E][F][D]
  unsigned short* w2t    = (unsigned short*)(ws + 84476416);  // 64 MiB [E][D][F]
  unsigned short* h_buf  = (unsigned short*)(ws + 151585280); // 128 MiB [2T][F]
  // y_buf aliases hs_bf + head of w1t: both fully rewritten every call before
  // any reader; y_buf written (MODE1) strictly after their last reader (MODE0).
  unsigned short* y_buf  = (unsigned short*)(ws + 590336);    // 32 MiB [2T][D]

  zero_counts_kernel<<<1, 64, 0, stream>>>(counts);
  router_kernel<<<TOKENS / 4, 256, 0, stream>>>(hs, gw, gb, counts, tok_idx, tok_w,
                                                slotinfo, hs_bf);
  scan_kernel<<<1, 64, 0, stream>>>(counts, offs);
  cast_transpose_kernel<<<dim3(FDIM / 64, DIM / 64, NEXP), 256, 0, stream>>>(w1, w1t, DIM, FDIM);
  cast_transpose_kernel<<<dim3(DIM / 64, FDIM / 64, NEXP), 256, 0, stream>>>(w2, w2t, FDIM, DIM);
  moe_gemm<0, DIM, FDIM><<<dim3(FDIM / 256, TOKENS / 256, NEXP), 512, 0, stream>>>(
      hs_bf, w1t, b1, counts, offs, tok_idx, h_buf);
  moe_gemm<1, FDIM, DIM><<<dim3(DIM / 256, TOKENS / 256, NEXP), 512, 0, stream>>>(
      h_buf, w2t, b2, counts, offs, tok_idx, y_buf);
  ln_combine_kernel<<<TOKENS / 4, 256, 0, stream>>>(y_buf, in_t, offs, slotinfo,
                                                    tok_w, gamma, beta, out);
}

// Round 4
// 767.807 us; speedup vs baseline: 1.3389x; 1.0397x over previous
//
#include <hip/hip_runtime.h>

#define TOKENS 8192
#define DIM 1024
#define NEXP 8
#define FDIM 4096

typedef __bf16 bf16x8 __attribute__((ext_vector_type(8)));
typedef float f32x4 __attribute__((ext_vector_type(4)));

__device__ __forceinline__ unsigned short f2bf(float f) {
  unsigned u = __builtin_bit_cast(unsigned, f);
  u += 0x7fffu + ((u >> 16) & 1u);
  return (unsigned short)(u >> 16);
}

__device__ __forceinline__ float bf2f(unsigned short s) {
  unsigned u = (unsigned)s << 16;
  return __builtin_bit_cast(float, u);
}

__device__ __forceinline__ void gload16(const void* g, void* l) {
  __builtin_amdgcn_global_load_lds(
      (const __attribute__((address_space(1))) unsigned int*)g,
      (__attribute__((address_space(3))) unsigned int*)l, 16, 0, 0);
}

// ---------------- router ----------------
__global__ void zero_counts_kernel(int* counts) {
  if (threadIdx.x < NEXP) counts[threadIdx.x] = 0;
}

__global__ void scan_kernel(const int* counts, int* offs) {
  if (threadIdx.x == 0) {
    int s = 0;
    for (int e = 0; e < NEXP; ++e) { offs[e] = s; s += counts[e]; }
    offs[NEXP] = s;
  }
}

__global__ void router_kernel(const float* __restrict__ hs,
                              const float* __restrict__ gw,
                              const float* __restrict__ gb,
                              int* __restrict__ counts,
                              int* __restrict__ tok_idx,
                              float* __restrict__ tok_w,
                              unsigned int* __restrict__ slotinfo,
                              unsigned short* __restrict__ hs_bf) {
  const int lane = threadIdx.x & 63;
  const int wid = threadIdx.x >> 6;
  const int t = blockIdx.x * 4 + wid;
  const float* row = hs + (size_t)t * DIM;

  float x[16];
  const float4* r4 = (const float4*)(row + lane * 16);
#pragma unroll
  for (int i = 0; i < 4; ++i) {
    float4 v = r4[i];
    x[i * 4 + 0] = v.x; x[i * 4 + 1] = v.y; x[i * 4 + 2] = v.z; x[i * 4 + 3] = v.w;
  }

  float acc[8];
#pragma unroll
  for (int e = 0; e < 8; ++e) acc[e] = 0.f;
#pragma unroll
  for (int i = 0; i < 16; ++i) {
    const int d = lane * 16 + i;
    const float4* g4 = (const float4*)(gw + (size_t)d * 8);
    float4 g0 = g4[0], g1 = g4[1];
    const float xv = x[i];
    acc[0] += xv * g0.x; acc[1] += xv * g0.y; acc[2] += xv * g0.z; acc[3] += xv * g0.w;
    acc[4] += xv * g1.x; acc[5] += xv * g1.y; acc[6] += xv * g1.z; acc[7] += xv * g1.w;
  }
#pragma unroll
  for (int sh = 1; sh < 64; sh <<= 1) {
#pragma unroll
    for (int e = 0; e < 8; ++e) acc[e] += __shfl_xor(acc[e], sh, 64);
  }
#pragma unroll
  for (int e = 0; e < 8; ++e) acc[e] += gb[e];

  float mx = acc[0];
#pragma unroll
  for (int e = 1; e < 8; ++e) mx = fmaxf(mx, acc[e]);
  float p[8];
  float sum = 0.f;
#pragma unroll
  for (int e = 0; e < 8; ++e) { p[e] = __expf(acc[e] - mx); sum += p[e]; }
  const float inv = 1.0f / sum;

  int i0 = 0; float b0 = p[0];
#pragma unroll
  for (int e = 1; e < 8; ++e) if (p[e] > b0) { b0 = p[e]; i0 = e; }
  int i1 = -1; float b1v = -1.f;
#pragma unroll
  for (int e = 0; e < 8; ++e) if (e != i0 && p[e] > b1v) { b1v = p[e]; i1 = e; }

  if (lane == 0) {
    int pos0 = atomicAdd(&counts[i0], 1);
    tok_idx[i0 * TOKENS + pos0] = t;
    tok_w[i0 * TOKENS + pos0] = b0 * inv;
    slotinfo[t * 2 + 0] = ((unsigned)i0 << 13) | (unsigned)pos0;
    int pos1 = atomicAdd(&counts[i1], 1);
    tok_idx[i1 * TOKENS + pos1] = t;
    tok_w[i1 * TOKENS + pos1] = b1v * inv;
    slotinfo[t * 2 + 1] = ((unsigned)i1 << 13) | (unsigned)pos1;
  }

  unsigned short us[16];
#pragma unroll
  for (int i = 0; i < 16; ++i) us[i] = f2bf(x[i]);
  uint4 o0, o1;
  o0.x = (unsigned)us[0] | ((unsigned)us[1] << 16);
  o0.y = (unsigned)us[2] | ((unsigned)us[3] << 16);
  o0.z = (unsigned)us[4] | ((unsigned)us[5] << 16);
  o0.w = (unsigned)us[6] | ((unsigned)us[7] << 16);
  o1.x = (unsigned)us[8] | ((unsigned)us[9] << 16);
  o1.y = (unsigned)us[10] | ((unsigned)us[11] << 16);
  o1.z = (unsigned)us[12] | ((unsigned)us[13] << 16);
  o1.w = (unsigned)us[14] | ((unsigned)us[15] << 16);
  uint4* dst = (uint4*)(hs_bf + (size_t)t * DIM + lane * 16);
  dst[0] = o0;
  dst[1] = o1;
}

// ---------------- transpose + cast weights: src[e][R][C] f32 -> dst[e][C][R] bf16 ----------------
__global__ void cast_transpose_kernel(const float* __restrict__ src,
                                      unsigned short* __restrict__ dst,
                                      int R, int C) {
  __shared__ float tile[64][65];
  const int e = blockIdx.z;
  const int r0 = blockIdx.y * 64;
  const int c0 = blockIdx.x * 64;
  const float* s = src + (size_t)e * R * C;
  unsigned int* d = (unsigned int*)(dst + (size_t)e * R * C);

#pragma unroll
  for (int i = 0; i < 16; ++i) {
    const int idx = threadIdx.x + i * 256;
    const int r = idx >> 6;
    const int c = idx & 63;
    tile[r][c] = s[(size_t)(r0 + r) * C + (c0 + c)];
  }
  __syncthreads();
#pragma unroll
  for (int i = 0; i < 8; ++i) {
    const int idx = threadIdx.x + i * 256;
    const int c = idx >> 5;
    const int r = (idx & 31) * 2;
    unsigned pk = (unsigned)f2bf(tile[r][c]) | ((unsigned)f2bf(tile[r + 1][c]) << 16);
    d[((size_t)(c0 + c) * R + (r0 + r)) >> 1] = pk;
  }
}

// ---------------- grouped GEMM: 256x256 tile, BK=32, 4-slot LDS ring ----------------
// Software-pipelined: 2 MFMA clusters/K-tile, 1 s_barrier/K-tile, counted vmcnt,
// register double-buffered fragments so ds_reads overlap the previous MFMA cluster.
//
// Ring safety: reads of tile t's slot all complete before the mid-tile barrier of t
// (a0/b0 via auto-waitcnt before C0; a1 via explicit lgkmcnt(0) in the gate);
// writes to that slot (tile t+4's staging) are issued only after that barrier.
// vmcnt(6) at tile t == "all of tile t+1's 4 staging loads landed" (newest-6 are
// A(t+2),B(t+2),A(t+3)); the barrier then propagates this across all 8 waves before
// any wave reads tile t+1's slot.

#define DO_TILE(sTp, sNp, A0C, B0C, A0N, B0N, STA, STB, WSA, GATESTR, READN, FINAL)   \
  {                                                                                   \
    bf16x8 a1r[4];                                                                    \
    _Pragma("unroll") for (int f_ = 0; f_ < 4; ++f_)                                  \
      a1r[f_] = *(const bf16x8*)((sTp) + aoff[4 + f_]);                               \
    if (STA) {                                                                        \
      gload16(aS0, (WSA));                                                            \
      gload16(aS1, (WSA) + 8192);                                                     \
      aS0 += 64; aS1 += 64;                                                           \
    }                                                                                 \
    __builtin_amdgcn_sched_barrier(0);                                                \
    __builtin_amdgcn_s_setprio(1);                                                    \
    _Pragma("unroll") for (int f_ = 0; f_ < 4; ++f_)                                  \
      _Pragma("unroll") for (int g_ = 0; g_ < 4; ++g_)                                \
        acc[f_][g_] = __builtin_amdgcn_mfma_f32_16x16x32_bf16(                        \
            A0C[f_], B0C[g_], acc[f_][g_], 0, 0, 0);                                  \
    __builtin_amdgcn_s_setprio(0);                                                    \
    __builtin_amdgcn_sched_barrier(0);                                                \
    if (!(FINAL)) {                                                                   \
      asm volatile(GATESTR ::: "memory");                                             \
      __builtin_amdgcn_s_barrier();                                                   \
    }                                                                                 \
    if (READN) {                                                                      \
      _Pragma("unroll") for (int f_ = 0; f_ < 4; ++f_)                                \
        A0N[f_] = *(const bf16x8*)((sNp) + aoff[f_]);                                 \
      _Pragma("unroll") for (int g_ = 0; g_ < 4; ++g_)                                \
        B0N[g_] = *(const bf16x8*)((sNp) + 65536 + boff[g_]);                         \
    }                                                                                 \
    if (STB) {                                                                        \
      gload16(bS0, (WSA) + 65536);                                                    \
      gload16(bS1, (WSA) + 65536 + 8192);                                             \
      bS0 += 64; bS1 += 64;                                                           \
    }                                                                                 \
    __builtin_amdgcn_sched_barrier(0);                                                \
    __builtin_amdgcn_s_setprio(1);                                                    \
    _Pragma("unroll") for (int f_ = 0; f_ < 4; ++f_)                                  \
      _Pragma("unroll") for (int g_ = 0; g_ < 4; ++g_)                                \
        acc[4 + f_][g_] = __builtin_amdgcn_mfma_f32_16x16x32_bf16(                    \
            a1r[f_], B0C[g_], acc[4 + f_][g_], 0, 0, 0);                              \
    __builtin_amdgcn_s_setprio(0);                                                    \
    __builtin_amdgcn_sched_barrier(0);                                                \
  }

template<int MODE, int K, int N>
__global__ __launch_bounds__(512, 2)
void moe_gemm(const unsigned short* __restrict__ Abase,
              const unsigned short* __restrict__ Bbase,
              const float* __restrict__ bias,
              const int* __restrict__ counts,
              const int* __restrict__ offs,
              const int* __restrict__ tok_idx,
              unsigned short* __restrict__ dst) {
  constexpr int NT = K / 32;  // K-tiles (multiple of 4, >= 8)
  __shared__ __align__(16) unsigned char sm[131072];

  const int e = blockIdx.z;
  const int cnt = counts[e];
  const int m0 = blockIdx.y * 256;
  if (m0 >= cnt) return;
  const int n0 = blockIdx.x * 256;
  const int goff = offs[e];

  const int tid = threadIdx.x;
  const int lane = tid & 63;
  const int wid = tid >> 6;
  const int wr = wid >> 2;   // 0..1 : M band (128 rows)
  const int wcn = wid & 3;   // 0..3 : N band (64 cols)
  const int l15 = lane & 15;
  const int cg = lane >> 4;  // 0..3 : 16B chunk group within 64B row
  const int wdst = wid * 1024;

  // ---- staging source addresses (per thread: rows urow and urow+128) ----
  const int urow = tid >> 2;
  const int uchk = tid & 3;
  const int swz = uchk ^ ((urow >> 1) & 3);  // source pre-swizzle (read-side matched)
  const unsigned char* Bexp = (const unsigned char*)(Bbase + (size_t)e * K * N);

  int gA0 = m0 + urow;       if (gA0 > cnt - 1) gA0 = cnt - 1;
  int gA1 = m0 + urow + 128; if (gA1 > cnt - 1) gA1 = cnt - 1;
  size_t rowA0, rowA1;
  if (MODE == 0) {
    rowA0 = (size_t)tok_idx[e * TOKENS + gA0] * K;
    rowA1 = (size_t)tok_idx[e * TOKENS + gA1] * K;
  } else {
    rowA0 = (size_t)(goff + gA0) * K;
    rowA1 = (size_t)(goff + gA1) * K;
  }
  const unsigned char* aS0 = (const unsigned char*)(Abase + rowA0) + swz * 16;
  const unsigned char* aS1 = (const unsigned char*)(Abase + rowA1) + swz * 16;
  const unsigned char* bS0 = Bexp + (size_t)(n0 + urow) * (K * 2) + swz * 16;
  const unsigned char* bS1 = Bexp + (size_t)(n0 + urow + 128) * (K * 2) + swz * 16;

  // ---- ds_read fragment byte offsets (loop-invariant) ----
  int aoff[8], boff[4];
#pragma unroll
  for (int f = 0; f < 8; ++f) {
    const int r = wr * 128 + f * 16 + l15;
    aoff[f] = r * 64 + ((cg ^ ((r >> 1) & 3)) * 16);
  }
#pragma unroll
  for (int g = 0; g < 4; ++g) {
    const int r = wcn * 64 + g * 16 + l15;
    boff[g] = r * 64 + ((cg ^ ((r >> 1) & 3)) * 16);
  }

  f32x4 acc[8][4];
  const f32x4 fz = {0.f, 0.f, 0.f, 0.f};
#pragma unroll
  for (int f = 0; f < 8; ++f)
#pragma unroll
    for (int g = 0; g < 4; ++g) acc[f][g] = fz;

  // ---- prologue: stage K-tiles 0,1,2 (issue order A0,B0,A1,B1,A2,B2) ----
#pragma unroll
  for (int j = 0; j < 3; ++j) {
    gload16(aS0, sm + j * 16384 + wdst);
    gload16(aS1, sm + j * 16384 + wdst + 8192);
    aS0 += 64; aS1 += 64;
    gload16(bS0, sm + 65536 + j * 16384 + wdst);
    gload16(bS1, sm + 65536 + j * 16384 + wdst + 8192);
    bS0 += 64; bS1 += 64;
  }
  asm volatile("s_waitcnt vmcnt(8)" ::: "memory");  // tile 0 (oldest 4 loads) landed
  __builtin_amdgcn_sched_barrier(0);
  __builtin_amdgcn_s_barrier();

  const unsigned char* smc = (const unsigned char*)sm;
  bf16x8 a0A[4], b0A[4], a0B[4], b0B[4];
#pragma unroll
  for (int f = 0; f < 4; ++f) a0A[f] = *(const bf16x8*)(smc + aoff[f]);
#pragma unroll
  for (int g = 0; g < 4; ++g) b0A[g] = *(const bf16x8*)(smc + 65536 + boff[g]);

  // ---- main loop: 2 K-tiles per iteration, full staging ----
  int t = 0;
#pragma unroll 1
  for (; t + 5 < NT; t += 2) {
    const unsigned char* sT0 = smc + ((t & 3) << 14);
    const unsigned char* sT1 = smc + (((t + 1) & 3) << 14);
    const unsigned char* sT2 = smc + (((t + 2) & 3) << 14);
    unsigned char* w3 = (unsigned char*)sm + (((t + 3) & 3) << 14) + wdst;
    unsigned char* w4 = (unsigned char*)sm + (((t + 4) & 3) << 14) + wdst;
    DO_TILE(sT0, sT1, a0A, b0A, a0B, b0B, 1, 1, w3,
            "s_waitcnt vmcnt(6) lgkmcnt(0)", 1, 0);
    DO_TILE(sT1, sT2, a0B, b0B, a0A, b0A, 1, 1, w4,
            "s_waitcnt vmcnt(6) lgkmcnt(0)", 1, 0);
  }
  // ---- tail: tiles NT-4..NT-1 (t == NT-4 here) ----
  {
    const unsigned char* sT0 = smc + ((t & 3) << 14);
    const unsigned char* sT1 = smc + (((t + 1) & 3) << 14);
    const unsigned char* sT2 = smc + (((t + 2) & 3) << 14);
    const unsigned char* sT3 = smc + (((t + 3) & 3) << 14);
    unsigned char* w3 = (unsigned char*)sm + (((t + 3) & 3) << 14) + wdst;
    DO_TILE(sT0, sT1, a0A, b0A, a0B, b0B, 1, 1, w3,
            "s_waitcnt vmcnt(6) lgkmcnt(0)", 1, 0);       // tile NT-4 (stages NT-1)
    DO_TILE(sT1, sT2, a0B, b0B, a0A, b0A, 0, 0, w3,
            "s_waitcnt vmcnt(4) lgkmcnt(0)", 1, 0);       // tile NT-3
    DO_TILE(sT2, sT3, a0A, b0A, a0B, b0B, 0, 0, w3,
            "s_waitcnt vmcnt(0) lgkmcnt(0)", 1, 0);       // tile NT-2
    DO_TILE(sT3, sT3, a0B, b0B, a0A, b0A, 0, 0, w3,
            "", 0, 1);                                    // tile NT-1 (final)
  }

  // ---- epilogue ----
#pragma unroll
  for (int g = 0; g < 4; ++g) {
    const int fcol = n0 + wcn * 64 + g * 16 + l15;
    const float bv = bias[e * N + fcol];
#pragma unroll
    for (int f = 0; f < 8; ++f) {
#pragma unroll
      for (int j = 0; j < 4; ++j) {
        const int ml = wr * 128 + f * 16 + cg * 4 + j;
        const int gm = m0 + ml;
        if (gm < cnt) {
          float v = acc[f][g][j] + bv;
          if (MODE == 0) {
            const float u = 0.7978845608028654f * (v + 0.044715f * v * v * v);
            const float th = 1.0f - 2.0f / (1.0f + __expf(2.0f * u));
            v = 0.5f * v * (1.0f + th);
          }
          dst[(size_t)(goff + gm) * N + fcol] = f2bf(v);
        }
      }
    }
  }
}

// ---------------- fused combine + residual + layernorm ----------------
__global__ void ln_combine_kernel(const unsigned short* __restrict__ y_buf,
                                  const float* __restrict__ in_t,
                                  const int* __restrict__ offs,
                                  const unsigned int* __restrict__ slotinfo,
                                  const float* __restrict__ tok_w,
                                  const float* __restrict__ gamma,
                                  const float* __restrict__ beta,
                                  float* __restrict__ out) {
  const int lane = threadIdx.x & 63;
  const int wid = threadIdx.x >> 6;
  const int t = blockIdx.x * 4 + wid;

  const unsigned s0 = slotinfo[t * 2 + 0];
  const unsigned s1 = slotinfo[t * 2 + 1];
  const int e0 = s0 >> 13, p0 = s0 & 8191;
  const int e1 = s1 >> 13, p1 = s1 & 8191;
  const float w0 = tok_w[e0 * TOKENS + p0];
  const float w1 = tok_w[e1 * TOKENS + p1];
  const size_t r0 = (size_t)(offs[e0] + p0) * DIM;
  const size_t r1 = (size_t)(offs[e1] + p1) * DIM;

  float v[16];
  {
    const float4* i4 = (const float4*)(in_t + (size_t)t * DIM + lane * 16);
    const uint4* y0 = (const uint4*)(y_buf + r0 + lane * 16);
    const uint4* y1 = (const uint4*)(y_buf + r1 + lane * 16);
#pragma unroll
    for (int i = 0; i < 4; ++i) {
      float4 a = i4[i];
      v[i * 4 + 0] = a.x; v[i * 4 + 1] = a.y; v[i * 4 + 2] = a.z; v[i * 4 + 3] = a.w;
    }
#pragma unroll
    for (int i = 0; i < 2; ++i) {
      uint4 u0 = y0[i];
      uint4 u1 = y1[i];
      const unsigned uw0[4] = {u0.x, u0.y, u0.z, u0.w};
      const unsigned uw1[4] = {u1.x, u1.y, u1.z, u1.w};
#pragma unroll
      for (int k = 0; k < 4; ++k) {
        const int base = i * 8 + k * 2;
        v[base + 0] += w0 * bf2f((unsigned short)(uw0[k] & 0xffff)) +
                       w1 * bf2f((unsigned short)(uw1[k] & 0xffff));
        v[base + 1] += w0 * bf2f((unsigned short)(uw0[k] >> 16)) +
                       w1 * bf2f((unsigned short)(uw1[k] >> 16));
      }
    }
  }

  float s = 0.f, s2 = 0.f;
#pragma unroll
  for (int i = 0; i < 16; ++i) { s += v[i]; s2 += v[i] * v[i]; }
#pragma unroll
  for (int sh = 1; sh < 64; sh <<= 1) {
    s += __shfl_xor(s, sh, 64);
    s2 += __shfl_xor(s2, sh, 64);
  }
  const float mu = s * (1.0f / DIM);
  const float var = s2 * (1.0f / DIM) - mu * mu;
  const float rs = rsqrtf(var + 1e-5f);

  float4* w4 = (float4*)(out + (size_t)t * DIM + lane * 16);
#pragma unroll
  for (int i = 0; i < 4; ++i) {
    const int d = lane * 16 + i * 4;
    float4 g = *(const float4*)(gamma + d);
    float4 b = *(const float4*)(beta + d);
    float4 o;
    o.x = (v[i * 4 + 0] - mu) * rs * g.x + b.x;
    o.y = (v[i * 4 + 1] - mu) * rs * g.y + b.y;
    o.z = (v[i * 4 + 2] - mu) * rs * g.z + b.z;
    o.w = (v[i * 4 + 3] - mu) * rs * g.w + b.w;
    w4[i] = o;
  }
}

extern "C" void kernel_launch(void* const* d_in, const int* in_sizes, int n_in,
                              void* d_out, int out_size, void* d_ws, size_t ws_size,
                              hipStream_t stream) {
  const float* hs    = (const float*)d_in[0];
  const float* in_t  = (const float*)d_in[1];
  const float* gw    = (const float*)d_in[2];
  const float* gb    = (const float*)d_in[3];
  const float* w1    = (const float*)d_in[4];
  const float* b1    = (const float*)d_in[5];
  const float* w2    = (const float*)d_in[6];
  const float* b2    = (const float*)d_in[7];
  const float* gamma = (const float*)d_in[8];
  const float* beta  = (const float*)d_in[9];
  float* out = (float*)d_out;
  char* ws = (char*)d_ws;

  // workspace layout (bytes)
  int* counts            = (int*)(ws + 0);                    // 32
  int* offs              = (int*)(ws + 256);                  // 36
  unsigned int* slotinfo = (unsigned int*)(ws + 512);         // 64 KiB
  int* tok_idx           = (int*)(ws + 66048);                // 256 KiB
  float* tok_w           = (float*)(ws + 328192);             // 256 KiB
  unsigned short* hs_bf  = (unsigned short*)(ws + 590336);    // 16 MiB
  unsigned short* w1t    = (unsigned short*)(ws + 17367552);  // 64 MiB [E][F][D]
  unsigned short* w2t    = (unsigned short*)(ws + 84476416);  // 64 MiB [E][D][F]
  unsigned short* h_buf  = (unsigned short*)(ws + 151585280); // 128 MiB [2T][F]
  // y_buf aliases hs_bf + head of w1t: both fully rewritten every call before
  // any reader; y_buf written (MODE1) strictly after their last reader (MODE0).
  unsigned short* y_buf  = (unsigned short*)(ws + 590336);    // 32 MiB [2T][D]

  zero_counts_kernel<<<1, 64, 0, stream>>>(counts);
  router_kernel<<<TOKENS / 4, 256, 0, stream>>>(hs, gw, gb, counts, tok_idx, tok_w,
                                                slotinfo, hs_bf);
  scan_kernel<<<1, 64, 0, stream>>>(counts, offs);
  cast_transpose_kernel<<<dim3(FDIM / 64, DIM / 64, NEXP), 256, 0, stream>>>(w1, w1t, DIM, FDIM);
  cast_transpose_kernel<<<dim3(DIM / 64, FDIM / 64, NEXP), 256, 0, stream>>>(w2, w2t, FDIM, DIM);
  moe_gemm<0, DIM, FDIM><<<dim3(FDIM / 256, TOKENS / 256, NEXP), 512, 0, stream>>>(
      hs_bf, w1t, b1, counts, offs, tok_idx, h_buf);
  moe_gemm<1, FDIM, DIM><<<dim3(DIM / 256, TOKENS / 256, NEXP), 512, 0, stream>>>(
      h_buf, w2t, b2, counts, offs, tok_idx, y_buf);
  ln_combine_kernel<<<TOKENS / 4, 256, 0, stream>>>(y_buf, in_t, offs, slotinfo,
                                                    tok_w, gamma, beta, out);
}